// Round 1
// baseline (554.106 us; speedup 1.0000x reference)
//
#include <hip/hip_runtime.h>
#include <stdint.h>

typedef __attribute__((ext_vector_type(8))) short short8;
typedef __attribute__((ext_vector_type(4))) float float4v;

__device__ __forceinline__ unsigned short f2b(float f){
  unsigned int x = __float_as_uint(f);
  x += 0x7fffu + ((x >> 16) & 1u);
  return (unsigned short)(x >> 16);
}
__device__ __forceinline__ unsigned int pk2(float lo, float hi){
  return (unsigned int)f2b(lo) | ((unsigned int)f2b(hi) << 16);
}
__device__ __forceinline__ float silu_f(float x){ return x / (1.0f + __expf(-x)); }
__device__ __forceinline__ float cutoff_f(float d){
  float c = 0.5f * (__cosf(d * 0.62831853071795864f) + 1.0f);
  return (d < 5.0f) ? c : 0.0f;
}

// ---------------- MFMA GEMM core: 128x128 tile, K=512, A fp32 (lda=512),
// ---------------- B pre-transposed bf16 [col][k] (ldb=512)
__device__ __forceinline__ void gemm_core(const float* __restrict__ A,
                                          const unsigned short* __restrict__ Bt,
                                          int rbase, int cbase, float4v acc[4][4])
{
  __shared__ __align__(16) unsigned short Ash[128*40];
  __shared__ __align__(16) unsigned short Bsh[128*40];
  const int t = threadIdx.x;
  const int sr = t >> 1;            // 0..127 (staging row / staging col)
  const int sk = (t & 1) << 4;      // 0 / 16
  const int lane = t & 63, wv = t >> 6;
  const int wr = wv >> 1, wc = wv & 1;
  const int lr = lane & 15, lk = lane >> 4;

  const float* ag = A + (size_t)(rbase + sr) * 512 + sk;
  const unsigned short* bg = Bt + (size_t)(cbase + sr) * 512 + sk;
  unsigned short* ash = Ash + sr * 40 + sk;
  unsigned short* bsh = Bsh + sr * 40 + sk;
  const unsigned short* afp = Ash + (wr * 64 + lr) * 40 + lk * 8;
  const unsigned short* bfp = Bsh + (wc * 64 + lr) * 40 + lk * 8;

  for (int kk = 0; kk < 512; kk += 32) {
    __syncthreads();
    float4 a0 = *(const float4*)(ag + kk);
    float4 a1 = *(const float4*)(ag + kk + 4);
    float4 a2 = *(const float4*)(ag + kk + 8);
    float4 a3 = *(const float4*)(ag + kk + 12);
    uint4 b0 = *(const uint4*)(bg + kk);
    uint4 b1 = *(const uint4*)(bg + kk + 8);
    uint4 w0, w1;
    w0.x = pk2(a0.x, a0.y); w0.y = pk2(a0.z, a0.w);
    w0.z = pk2(a1.x, a1.y); w0.w = pk2(a1.z, a1.w);
    w1.x = pk2(a2.x, a2.y); w1.y = pk2(a2.z, a2.w);
    w1.z = pk2(a3.x, a3.y); w1.w = pk2(a3.z, a3.w);
    *(uint4*)(ash)     = w0;
    *(uint4*)(ash + 8) = w1;
    *(uint4*)(bsh)     = b0;
    *(uint4*)(bsh + 8) = b1;
    __syncthreads();
    short8 af[4], bf[4];
#pragma unroll
    for (int f = 0; f < 4; ++f) af[f] = *(const short8*)(afp + f * 640);
#pragma unroll
    for (int f = 0; f < 4; ++f) bf[f] = *(const short8*)(bfp + f * 640);
#pragma unroll
    for (int fr = 0; fr < 4; ++fr)
#pragma unroll
      for (int fc = 0; fc < 4; ++fc)
        acc[fr][fc] = __builtin_amdgcn_mfma_f32_16x16x32_bf16(af[fr], bf[fc], acc[fr][fc], 0, 0, 0);
  }
}

// ---------------- generic linear: out = A@W (+ rowscale*bias)
__global__ __launch_bounds__(256, 2) void gemm_lin(const float* __restrict__ A,
    const unsigned short* __restrict__ Bt, const float* __restrict__ bias,
    const float* __restrict__ rowscale, float* __restrict__ out, int ldc, int nct)
{
  int b = blockIdx.x;
  int ct = b % nct, rt = b / nct;
  int rbase = rt * 128, cbase = ct * 128;
  float4v acc[4][4];
#pragma unroll
  for (int fr = 0; fr < 4; ++fr)
#pragma unroll
    for (int fc = 0; fc < 4; ++fc) acc[fr][fc] = (float4v){0.f,0.f,0.f,0.f};
  gemm_core(A, Bt, rbase, cbase, acc);

  const int t = threadIdx.x;
  const int lane = t & 63, wv = t >> 6;
  const int wr = wv >> 1, wc = wv & 1;
  const int lr = lane & 15, lk = lane >> 4;
#pragma unroll
  for (int fr = 0; fr < 4; ++fr)
#pragma unroll
    for (int i = 0; i < 4; ++i) {
      int grow = rbase + wr * 64 + fr * 16 + lk * 4 + i;
      float rs = rowscale ? rowscale[grow] : 1.0f;
#pragma unroll
      for (int fc = 0; fc < 4; ++fc) {
        int col = cbase + wc * 64 + fc * 16 + lr;
        float vv = acc[fr][fc][i];
        if (bias) vv += rs * bias[col];
        out[(size_t)grow * ldc + col] = vv;
      }
    }
}

// ---------------- pass 1: attn_probs = silu(ksum * (q . silu(EA@Wdk+bdk))) * cutoff(dist)
__global__ __launch_bounds__(256, 2) void gemm_attn(const float* __restrict__ EA,
    const unsigned short* __restrict__ Wdkt, const float* __restrict__ bdk,
    const float* __restrict__ q, const float* __restrict__ ksum,
    const float* __restrict__ dist, float* __restrict__ apout)
{
  int b = blockIdx.x;
  int xcd = b & 7, slot = b >> 3;
  int ct = slot & 3, rt = (slot >> 2) * 8 + xcd;   // 4 col-tiles of one row-tile share an XCD
  int rbase = rt * 128, cbase = ct * 128;
  float4v acc[4][4];
#pragma unroll
  for (int fr = 0; fr < 4; ++fr)
#pragma unroll
    for (int fc = 0; fc < 4; ++fc) acc[fr][fc] = (float4v){0.f,0.f,0.f,0.f};
  gemm_core(EA, Wdkt, rbase, cbase, acc);

  const int t = threadIdx.x;
  const int lane = t & 63, wv = t >> 6;
  const int wr = wv >> 1, wc = wv & 1;
  const int lr = lane & 15, lk = lane >> 4;

  int n = rbase >> 8, mb = rbase & 255;
  int h = (cbase >> 6) + wc;           // head covered by this wave
  float ks = ksum[h * 256 + n];
  float qv[4], bv[4];
#pragma unroll
  for (int fc = 0; fc < 4; ++fc) {
    int col = cbase + wc * 64 + fc * 16 + lr;
    qv[fc] = q[n * 512 + col];
    bv[fc] = bdk[col];
  }
#pragma unroll
  for (int fr = 0; fr < 4; ++fr)
#pragma unroll
    for (int i = 0; i < 4; ++i) {
      float s = 0.f;
#pragma unroll
      for (int fc = 0; fc < 4; ++fc)
        s += silu_f(acc[fr][fc][i] + bv[fc]) * qv[fc];
      s += __shfl_xor(s, 1); s += __shfl_xor(s, 2);
      s += __shfl_xor(s, 4); s += __shfl_xor(s, 8);
      int m = mb + wr * 64 + fr * 16 + lk * 4 + i;
      if (lr == 0) {
        float pr = silu_f(ks * s) * cutoff_f(dist[n * 256 + m]);
        apout[h * 65536 + n * 256 + m] = pr;
      }
    }
}

// ---------------- pass 2: ipe = silu(EA@Wea+bea) * sum_c ws[i,c,e]*wt[j,c,e]
__global__ __launch_bounds__(256, 2) void gemm_ipe(const float* __restrict__ EA,
    const unsigned short* __restrict__ Weat, const float* __restrict__ bea,
    const float* __restrict__ wswt, float* __restrict__ ipe)
{
  int b = blockIdx.x;
  int xcd = b & 7, slot = b >> 3;
  int ct = slot & 3, rt = (slot >> 2) * 8 + xcd;
  int rbase = rt * 128, cbase = ct * 128;
  float4v acc[4][4];
#pragma unroll
  for (int fr = 0; fr < 4; ++fr)
#pragma unroll
    for (int fc = 0; fc < 4; ++fc) acc[fr][fc] = (float4v){0.f,0.f,0.f,0.f};
  gemm_core(EA, Weat, rbase, cbase, acc);

  const int t = threadIdx.x;
  const int lane = t & 63, wv = t >> 6;
  const int wr = wv >> 1, wc = wv & 1;
  const int lr = lane & 15, lk = lane >> 4;

  int i_n = rbase >> 8, jb = rbase & 255;
  float bv[4], wsv[4][3];
#pragma unroll
  for (int fc = 0; fc < 4; ++fc) {
    int col = cbase + wc * 64 + fc * 16 + lr;
    bv[fc] = bea[col];
#pragma unroll
    for (int c = 0; c < 3; ++c)
      wsv[fc][c] = wswt[(size_t)(i_n * 3 + c) * 1024 + col];
  }
#pragma unroll
  for (int fr = 0; fr < 4; ++fr)
#pragma unroll
    for (int i = 0; i < 4; ++i) {
      int j = jb + wr * 64 + fr * 16 + lk * 4 + i;
      const float* wtp = wswt + (size_t)j * 3072 + 512;
      float* op = ipe + ((size_t)i_n * 256 + j) * 512;
#pragma unroll
      for (int fc = 0; fc < 4; ++fc) {
        int col = cbase + wc * 64 + fc * 16 + lr;
        float y = silu_f(acc[fr][fc][i] + bv[fc]);
        float s = wsv[fc][0] * wtp[col] + wsv[fc][1] * wtp[1024 + col]
                + wsv[fc][2] * wtp[2048 + col];
        op[col] = y * s;
      }
    }
}

// ---------------- transpose + fp32->bf16 convert: Wt[e][k] = bf16(W[k][e])
__global__ __launch_bounds__(256) void transp_bf16(const float* __restrict__ W,
    unsigned short* __restrict__ Wt, int K, int E)
{
  __shared__ unsigned short tl[32][36];
  int t = threadIdx.x;
  int r = t >> 3, c4 = (t & 7) * 4;
  int k0 = blockIdx.x * 32, e0 = blockIdx.y * 32;
  float4 f = *(const float4*)(W + (size_t)(k0 + r) * E + e0 + c4);
  tl[c4 + 0][r] = f2b(f.x);
  tl[c4 + 1][r] = f2b(f.y);
  tl[c4 + 2][r] = f2b(f.z);
  tl[c4 + 3][r] = f2b(f.w);
  __syncthreads();
  uint2 o;
  o.x = (unsigned int)tl[r][c4] | ((unsigned int)tl[r][c4 + 1] << 16);
  o.y = (unsigned int)tl[r][c4 + 2] | ((unsigned int)tl[r][c4 + 3] << 16);
  *(uint2*)(Wt + (size_t)(e0 + r) * K + k0 + c4) = o;
}

// ---------------- ksum[h][n] = sum_d k[n][h*64+d]
__global__ __launch_bounds__(256) void ksum_k(const float* __restrict__ kmat,
                                              float* __restrict__ ksum)
{
  int t = threadIdx.x, wv = t >> 6, lane = t & 63;
  int idx = blockIdx.x * 4 + wv;       // 0..2047
  int h = idx >> 8, n = idx & 255;
  float val = kmat[n * 512 + h * 64 + lane];
#pragma unroll
  for (int o = 1; o < 64; o <<= 1) val += __shfl_xor(val, o);
  if (lane == 0) ksum[h * 256 + n] = val;
}

// ---------------- stage C: attn out, Z[n][c][e], vsum[n][c]
__global__ __launch_bounds__(512) void stage_c(const float* __restrict__ ap,
    const float* __restrict__ v, const float* __restrict__ vec,
    float* __restrict__ attn_out, float* __restrict__ Z, float* __restrict__ vsum)
{
  __shared__ float aps[2048];    // [h][m]
  __shared__ float vecs[768];    // [c][m]
  int n = blockIdx.x, t = threadIdx.x;
  for (int i = t; i < 2048; i += 512) {
    int h = i >> 8, m = i & 255;
    aps[i] = ap[h * 65536 + n * 256 + m];
  }
  for (int i = t; i < 768; i += 512) {
    int m = i / 3, c = i - 3 * m;
    vecs[c * 256 + m] = vec[(n * 256 + m) * 3 + c];
  }
  __syncthreads();
  int h = t >> 6;
  const float* apn_row = aps + h * 256;
  float a_acc = 0.f, z0 = 0.f, z1 = 0.f, z2 = 0.f;
#pragma unroll 4
  for (int m = 0; m < 256; ++m) {
    float p = apn_row[m];
    float vl = v[m * 512 + t];
    float pv = p * vl;
    a_acc += pv;
    z0 += vecs[m] * pv;
    z1 += vecs[256 + m] * pv;
    z2 += vecs[512 + m] * pv;
  }
  attn_out[n * 512 + t] = a_acc;
  Z[(n * 3 + 0) * 512 + t] = z0;
  Z[(n * 3 + 1) * 512 + t] = z1;
  Z[(n * 3 + 2) * 512 + t] = z2;
  if (t < 3) {
    float s = 0.f;
    for (int m = 0; m < 256; ++m) s += vecs[t * 256 + m];
    vsum[n * 3 + t] = s;
  }
}

// ---------------- vec layer norm max-min, in-place on du (N,3,E)
__global__ __launch_bounds__(512) void vecnorm(float* __restrict__ du)
{
  __shared__ float smx[8], smn[8];
  int n = blockIdx.x, t = threadIdx.x;
  float d0 = du[(n * 3 + 0) * 512 + t];
  float d1 = du[(n * 3 + 1) * 512 + t];
  float d2 = du[(n * 3 + 2) * 512 + t];
  float norm = sqrtf(d0 * d0 + d1 * d1 + d2 * d2);
  norm = fmaxf(norm, 1e-12f);
  float mx = norm, mn = norm;
#pragma unroll
  for (int o = 1; o < 64; o <<= 1) {
    mx = fmaxf(mx, __shfl_xor(mx, o));
    mn = fminf(mn, __shfl_xor(mn, o));
  }
  if ((t & 63) == 0) { smx[t >> 6] = mx; smn[t >> 6] = mn; }
  __syncthreads();
  float gmx = smx[0], gmn = smn[0];
#pragma unroll
  for (int i = 1; i < 8; ++i) { gmx = fmaxf(gmx, smx[i]); gmn = fminf(gmn, smn[i]); }
  float delta = gmx - gmn;
  if (delta == 0.0f) delta = 1.0f;
  float dn = fmaxf((norm - gmn) / delta, 0.0f);
  float sc = dn / norm;
  du[(n * 3 + 0) * 512 + t] = d0 * sc;
  du[(n * 3 + 1) * 512 + t] = d1 * sc;
  du[(n * 3 + 2) * 512 + t] = d2 * sc;
}

extern "C" void kernel_launch(void* const* d_in, const int* in_sizes, int n_in,
                              void* d_out, int out_size, void* d_ws, size_t ws_size,
                              hipStream_t stream)
{
  const float* x    = (const float*)d_in[0];
  const float* vec  = (const float*)d_in[1];
  const float* dist = (const float*)d_in[2];
  const float* ea   = (const float*)d_in[3];
  const float* Wq   = (const float*)d_in[4];
  const float* bq   = (const float*)d_in[5];
  const float* Wk   = (const float*)d_in[6];
  const float* bk   = (const float*)d_in[7];
  const float* Wv   = (const float*)d_in[8];
  const float* bv   = (const float*)d_in[9];
  const float* Wdk  = (const float*)d_in[10];
  const float* bdk  = (const float*)d_in[11];
  const float* Wdu  = (const float*)d_in[12];
  const float* bdu  = (const float*)d_in[13];
  const float* Wdih = (const float*)d_in[14];
  const float* Wea  = (const float*)d_in[15];
  const float* bea  = (const float*)d_in[16];
  float* out_attn = (float*)d_out;
  float* out_ipe  = out_attn + 256 * 512;

  float* w = (float*)d_ws;
  float* qb    = w; w += 131072;
  float* kb    = w; w += 131072;
  float* vb    = w; w += 131072;
  float* ksumb = w; w += 2048;
  float* apb   = w; w += 524288;
  float* Zb    = w; w += 393216;
  float* vsumb = w; w += 768;
  float* dub   = w; w += 393216;
  float* wswtb = w; w += 786432;
  unsigned short* us = (unsigned short*)w;
  unsigned short* Wq_t   = us; us += 262144;
  unsigned short* Wk_t   = us; us += 262144;
  unsigned short* Wv_t   = us; us += 262144;
  unsigned short* Wdk_t  = us; us += 262144;
  unsigned short* Wdu_t  = us; us += 262144;
  unsigned short* Wea_t  = us; us += 262144;
  unsigned short* Wdih_t = us; us += 524288;

  dim3 b256(256), b512(512);

  transp_bf16<<<dim3(16, 16), b256, 0, stream>>>(Wq,   Wq_t,   512, 512);
  transp_bf16<<<dim3(16, 16), b256, 0, stream>>>(Wk,   Wk_t,   512, 512);
  transp_bf16<<<dim3(16, 16), b256, 0, stream>>>(Wv,   Wv_t,   512, 512);
  transp_bf16<<<dim3(16, 16), b256, 0, stream>>>(Wdk,  Wdk_t,  512, 512);
  transp_bf16<<<dim3(16, 16), b256, 0, stream>>>(Wdu,  Wdu_t,  512, 512);
  transp_bf16<<<dim3(16, 16), b256, 0, stream>>>(Wea,  Wea_t,  512, 512);
  transp_bf16<<<dim3(16, 32), b256, 0, stream>>>(Wdih, Wdih_t, 512, 1024);

  gemm_lin<<<8, b256, 0, stream>>>(x, Wq_t, bq, nullptr, qb, 512, 4);
  gemm_lin<<<8, b256, 0, stream>>>(x, Wk_t, bk, nullptr, kb, 512, 4);
  gemm_lin<<<8, b256, 0, stream>>>(x, Wv_t, bv, nullptr, vb, 512, 4);
  ksum_k<<<512, b256, 0, stream>>>(kb, ksumb);

  gemm_attn<<<2048, b256, 0, stream>>>(ea, Wdk_t, bdk, qb, ksumb, dist, apb);
  stage_c<<<256, b512, 0, stream>>>(apb, vb, vec, out_attn, Zb, vsumb);
  gemm_lin<<<24, b256, 0, stream>>>(Zb, Wdu_t, bdu, vsumb, dub, 512, 4);
  vecnorm<<<256, b512, 0, stream>>>(dub);
  gemm_lin<<<48, b256, 0, stream>>>(dub, Wdih_t, nullptr, nullptr, wswtb, 1024, 8);
  gemm_ipe<<<2048, b256, 0, stream>>>(ea, Wea_t, bea, wswtb, out_ipe);
}

// Round 2
// 455.666 us; speedup vs baseline: 1.2160x; 1.2160x over previous
//
#include <hip/hip_runtime.h>
#include <stdint.h>

typedef __attribute__((ext_vector_type(8))) short short8;
typedef __attribute__((ext_vector_type(4))) float float4v;

__device__ __forceinline__ unsigned short f2b(float f){
  unsigned int x = __float_as_uint(f);
  x += 0x7fffu + ((x >> 16) & 1u);
  return (unsigned short)(x >> 16);
}
__device__ __forceinline__ unsigned int pk2(float lo, float hi){
  return (unsigned int)f2b(lo) | ((unsigned int)f2b(hi) << 16);
}
__device__ __forceinline__ float silu_f(float x){ return x / (1.0f + __expf(-x)); }
__device__ __forceinline__ float cutoff_f(float d){
  float c = 0.5f * (__cosf(d * 0.62831853071795864f) + 1.0f);
  return (d < 5.0f) ? c : 0.0f;
}

__device__ __forceinline__ void gl_lds16(const unsigned short* g, unsigned short* l){
  __builtin_amdgcn_global_load_lds(
      (const __attribute__((address_space(1))) unsigned int*)g,
      (__attribute__((address_space(3))) unsigned int*)l, 16, 0, 0);
}

// ---------------- MFMA GEMM core: 128x128 tile, K=512, A,B bf16 [row][k] ld=512.
// global_load_lds (16B) staging, XOR k-chunk swizzle: LDS slot s of row r holds
// global k-chunk s ^ ((r>>1)&3) -> fragment ds_read_b128 is 2-way (free) not 8-way.
__device__ __forceinline__ void gemm_core_b(const unsigned short* __restrict__ A,
                                            const unsigned short* __restrict__ Bt,
                                            int rbase, int cbase, float4v acc[4][4])
{
  __shared__ __align__(16) unsigned short Ash[128*32];
  __shared__ __align__(16) unsigned short Bsh[128*32];
  const int t = threadIdx.x;
  const int lane = t & 63, wv = t >> 6;
  const int wr = wv >> 1, wc = wv & 1;
  const int lr = lane & 15, lk = lane >> 4;

  // staging: pass p in {0,1}: LDS byte off = p*4096 + wv*1024 + lane*16
  const int off0 = (wv << 10) + (lane << 4);
  const int row0 = off0 >> 6;                 // 0..63 (pass1: +64, same swizzle term)
  const int slot = (off0 >> 4) & 3;
  const int kc   = slot ^ ((row0 >> 1) & 3);
  const unsigned short* ag0 = A  + (size_t)(rbase + row0) * 512 + kc * 8;
  const unsigned short* bg0 = Bt + (size_t)(cbase + row0) * 512 + kc * 8;
  unsigned short* as0 = Ash + (off0 >> 1);
  unsigned short* bs0 = Bsh + (off0 >> 1);

  const int ra = wr * 64 + lr, sa = (ra >> 1) & 3;
  const int rb = wc * 64 + lr, sb = (rb >> 1) & 3;
  const unsigned short* afp = Ash + ra * 32 + ((lk ^ sa) << 3);
  const unsigned short* bfp = Bsh + rb * 32 + ((lk ^ sb) << 3);

  for (int kk = 0; kk < 512; kk += 32) {
    __syncthreads();
    gl_lds16(ag0 + kk,            as0);
    gl_lds16(ag0 + kk + 64 * 512, as0 + 2048);
    gl_lds16(bg0 + kk,            bs0);
    gl_lds16(bg0 + kk + 64 * 512, bs0 + 2048);
    __syncthreads();
    short8 af[4], bf[4];
#pragma unroll
    for (int f = 0; f < 4; ++f) af[f] = *(const short8*)(afp + f * 512);
#pragma unroll
    for (int f = 0; f < 4; ++f) bf[f] = *(const short8*)(bfp + f * 512);
#pragma unroll
    for (int fr = 0; fr < 4; ++fr)
#pragma unroll
      for (int fc = 0; fc < 4; ++fc)
        acc[fr][fc] = __builtin_amdgcn_mfma_f32_16x16x32_bf16(af[fr], bf[fc], acc[fr][fc], 0, 0, 0);
  }
}

// ---------------- generic linear: out = A@W (+ rowscale*bias)
__global__ __launch_bounds__(256, 4) void gemm_lin(const unsigned short* __restrict__ A,
    const unsigned short* __restrict__ Bt, const float* __restrict__ bias,
    const float* __restrict__ rowscale, float* __restrict__ out, int ldc, int nct)
{
  int b = blockIdx.x;
  int ct = b % nct, rt = b / nct;
  int rbase = rt * 128, cbase = ct * 128;
  float4v acc[4][4];
#pragma unroll
  for (int fr = 0; fr < 4; ++fr)
#pragma unroll
    for (int fc = 0; fc < 4; ++fc) acc[fr][fc] = (float4v){0.f,0.f,0.f,0.f};
  gemm_core_b(A, Bt, rbase, cbase, acc);

  const int t = threadIdx.x;
  const int lane = t & 63, wv = t >> 6;
  const int wr = wv >> 1, wc = wv & 1;
  const int lr = lane & 15, lk = lane >> 4;
#pragma unroll
  for (int fr = 0; fr < 4; ++fr)
#pragma unroll
    for (int i = 0; i < 4; ++i) {
      int grow = rbase + wr * 64 + fr * 16 + lk * 4 + i;
      float rs = rowscale ? rowscale[grow] : 1.0f;
#pragma unroll
      for (int fc = 0; fc < 4; ++fc) {
        int col = cbase + wc * 64 + fc * 16 + lr;
        float vv = acc[fr][fc][i];
        if (bias) vv += rs * bias[col];
        out[(size_t)grow * ldc + col] = vv;
      }
    }
}

// ---------------- fused qkv GEMM: out[256][1536] = x @ [Wq|Wk|Wv] + [bq|bk|bv]
// epilogue also computes ksum[h][n] = sum_d k[n][h*64+d]
__global__ __launch_bounds__(256, 4) void gemm_qkv(const unsigned short* __restrict__ A,
    const unsigned short* __restrict__ Bt, const float* __restrict__ bq,
    const float* __restrict__ bk, const float* __restrict__ bv,
    float* __restrict__ out, float* __restrict__ ksum)
{
  int b = blockIdx.x;
  int ct = b % 12, rt = b / 12;
  int rbase = rt * 128, cbase = ct * 128;
  float4v acc[4][4];
#pragma unroll
  for (int fr = 0; fr < 4; ++fr)
#pragma unroll
    for (int fc = 0; fc < 4; ++fc) acc[fr][fc] = (float4v){0.f,0.f,0.f,0.f};
  gemm_core_b(A, Bt, rbase, cbase, acc);

  const int t = threadIdx.x;
  const int lane = t & 63, wv = t >> 6;
  const int wr = wv >> 1, wc = wv & 1;
  const int lr = lane & 15, lk = lane >> 4;

  float bvv[4];
#pragma unroll
  for (int fc = 0; fc < 4; ++fc) {
    int col = cbase + wc * 64 + fc * 16 + lr;
    bvv[fc] = (col < 512) ? bq[col] : (col < 1024 ? bk[col - 512] : bv[col - 1024]);
  }
  bool isk = (cbase >= 512) && (cbase < 1024);
  int h = ((cbase - 512) >> 6) + wc;
#pragma unroll
  for (int fr = 0; fr < 4; ++fr)
#pragma unroll
    for (int i = 0; i < 4; ++i) {
      int grow = rbase + wr * 64 + fr * 16 + lk * 4 + i;
      float s = 0.f;
#pragma unroll
      for (int fc = 0; fc < 4; ++fc) {
        int col = cbase + wc * 64 + fc * 16 + lr;
        float vv = acc[fr][fc][i] + bvv[fc];
        out[(size_t)grow * 1536 + col] = vv;
        s += vv;
      }
      if (isk) {
        s += __shfl_xor(s, 1); s += __shfl_xor(s, 2);
        s += __shfl_xor(s, 4); s += __shfl_xor(s, 8);
        if (lr == 0) ksum[h * 256 + grow] = s;
      }
    }
}

// ---------------- pass 1: attn_probs = silu(ksum * (q . silu(EA@Wdk+bdk))) * cutoff(dist)
__global__ __launch_bounds__(256, 4) void gemm_attn(const unsigned short* __restrict__ EA,
    const unsigned short* __restrict__ Wdkt, const float* __restrict__ bdk,
    const float* __restrict__ qkv, const float* __restrict__ ksum,
    const float* __restrict__ dist, float* __restrict__ apout)
{
  int b = blockIdx.x;
  int xcd = b & 7, slot = b >> 3;
  int ct = slot & 3, rt = (slot >> 2) * 8 + xcd;   // 4 col-tiles of a row-tile share an XCD
  int rbase = rt * 128, cbase = ct * 128;
  float4v acc[4][4];
#pragma unroll
  for (int fr = 0; fr < 4; ++fr)
#pragma unroll
    for (int fc = 0; fc < 4; ++fc) acc[fr][fc] = (float4v){0.f,0.f,0.f,0.f};
  gemm_core_b(EA, Wdkt, rbase, cbase, acc);

  const int t = threadIdx.x;
  const int lane = t & 63, wv = t >> 6;
  const int wr = wv >> 1, wc = wv & 1;
  const int lr = lane & 15, lk = lane >> 4;

  int n = rbase >> 8, mb = rbase & 255;
  int h = (cbase >> 6) + wc;
  float ks = ksum[h * 256 + n];
  float qv[4], bv[4];
#pragma unroll
  for (int fc = 0; fc < 4; ++fc) {
    int col = cbase + wc * 64 + fc * 16 + lr;
    qv[fc] = qkv[n * 1536 + col];
    bv[fc] = bdk[col];
  }
#pragma unroll
  for (int fr = 0; fr < 4; ++fr)
#pragma unroll
    for (int i = 0; i < 4; ++i) {
      float s = 0.f;
#pragma unroll
      for (int fc = 0; fc < 4; ++fc)
        s += silu_f(acc[fr][fc][i] + bv[fc]) * qv[fc];
      s += __shfl_xor(s, 1); s += __shfl_xor(s, 2);
      s += __shfl_xor(s, 4); s += __shfl_xor(s, 8);
      int m = mb + wr * 64 + fr * 16 + lk * 4 + i;
      if (lr == 0) {
        float pr = silu_f(ks * s) * cutoff_f(dist[n * 256 + m]);
        apout[h * 65536 + n * 256 + m] = pr;
      }
    }
}

// ---------------- pass 2: ipe = silu(EA@Wea+bea) * sum_c ws[i,c,e]*wt[j,c,e]
__global__ __launch_bounds__(256, 4) void gemm_ipe(const unsigned short* __restrict__ EA,
    const unsigned short* __restrict__ Weat, const float* __restrict__ bea,
    const float* __restrict__ wswt, float* __restrict__ ipe)
{
  int b = blockIdx.x;
  int xcd = b & 7, slot = b >> 3;
  int ct = slot & 3, rt = (slot >> 2) * 8 + xcd;
  int rbase = rt * 128, cbase = ct * 128;
  float4v acc[4][4];
#pragma unroll
  for (int fr = 0; fr < 4; ++fr)
#pragma unroll
    for (int fc = 0; fc < 4; ++fc) acc[fr][fc] = (float4v){0.f,0.f,0.f,0.f};
  gemm_core_b(EA, Weat, rbase, cbase, acc);

  const int t = threadIdx.x;
  const int lane = t & 63, wv = t >> 6;
  const int wr = wv >> 1, wc = wv & 1;
  const int lr = lane & 15, lk = lane >> 4;

  int i_n = rbase >> 8, jb = rbase & 255;
  float bv[4], wsv[4][3];
#pragma unroll
  for (int fc = 0; fc < 4; ++fc) {
    int col = cbase + wc * 64 + fc * 16 + lr;
    bv[fc] = bea[col];
#pragma unroll
    for (int c = 0; c < 3; ++c)
      wsv[fc][c] = wswt[(size_t)(i_n * 3 + c) * 1024 + col];
  }
#pragma unroll
  for (int fr = 0; fr < 4; ++fr)
#pragma unroll
    for (int i = 0; i < 4; ++i) {
      int j = jb + wr * 64 + fr * 16 + lk * 4 + i;
      const float* wtp = wswt + (size_t)j * 3072 + 512;
      float* op = ipe + ((size_t)i_n * 256 + j) * 512;
#pragma unroll
      for (int fc = 0; fc < 4; ++fc) {
        int col = cbase + wc * 64 + fc * 16 + lr;
        float y = silu_f(acc[fr][fc][i] + bv[fc]);
        float s = wsv[fc][0] * wtp[col] + wsv[fc][1] * wtp[1024 + col]
                + wsv[fc][2] * wtp[2048 + col];
        op[col] = y * s;
      }
    }
}

// ---------------- fp32 -> bf16 convert (ea + x in one launch)
__global__ __launch_bounds__(256) void cvt_bf16(const float* __restrict__ ea,
    unsigned short* __restrict__ eab, const float* __restrict__ x,
    unsigned short* __restrict__ xb)
{
  int b = blockIdx.x, t = threadIdx.x;
  const float* src; unsigned short* dst; size_t base;
  if (b < 64) { src = x;  dst = xb;  base = (size_t)b * 2048; }
  else        { src = ea; dst = eab; base = (size_t)(b - 64) * 2048; }
  size_t i = base + (size_t)t * 8;
  float4 f0 = *(const float4*)(src + i);
  float4 f1 = *(const float4*)(src + i + 4);
  uint4 o;
  o.x = pk2(f0.x, f0.y); o.y = pk2(f0.z, f0.w);
  o.z = pk2(f1.x, f1.y); o.w = pk2(f1.z, f1.w);
  *(uint4*)(dst + i) = o;
}

// ---------------- all-weights transpose + bf16: Wt[e][k] = bf16(W[k][e]), K=512
struct TJobs { const float* src[7]; unsigned short* dst[7]; int E[7]; };
__global__ __launch_bounds__(256) void transp_all(TJobs jobs)
{
  __shared__ unsigned short tl[32][36];
  int j = blockIdx.z;
  int E = jobs.E[j];
  int e0 = blockIdx.y * 32;
  if (e0 >= E) return;
  const float* W = jobs.src[j];
  unsigned short* Wt = jobs.dst[j];
  int t = threadIdx.x;
  int r = t >> 3, c4 = (t & 7) * 4;
  int k0 = blockIdx.x * 32;
  float4 f = *(const float4*)(W + (size_t)(k0 + r) * E + e0 + c4);
  tl[c4 + 0][r] = f2b(f.x);
  tl[c4 + 1][r] = f2b(f.y);
  tl[c4 + 2][r] = f2b(f.z);
  tl[c4 + 3][r] = f2b(f.w);
  __syncthreads();
  uint2 o;
  o.x = (unsigned int)tl[r][c4] | ((unsigned int)tl[r][c4 + 1] << 16);
  o.y = (unsigned int)tl[r][c4 + 2] | ((unsigned int)tl[r][c4 + 3] << 16);
  *(uint2*)(Wt + (size_t)(e0 + r) * 512 + k0 + c4) = o;
}

// ---------------- stage C: attn out, Z bf16 [n][c][e], vsum[n][c]
__global__ __launch_bounds__(512) void stage_c(const float* __restrict__ ap,
    const float* __restrict__ qkv, const float* __restrict__ vec,
    float* __restrict__ attn_out, unsigned short* __restrict__ Z16,
    float* __restrict__ vsum)
{
  __shared__ float aps[2048];    // [h][m]
  __shared__ float vecs[768];    // [c][m]
  int n = blockIdx.x, t = threadIdx.x;
  for (int i = t; i < 2048; i += 512) {
    int h = i >> 8, m = i & 255;
    aps[i] = ap[h * 65536 + n * 256 + m];
  }
  for (int i = t; i < 768; i += 512) {
    int m = i / 3, c = i - 3 * m;
    vecs[c * 256 + m] = vec[(n * 256 + m) * 3 + c];
  }
  __syncthreads();
  int h = t >> 6;
  const float* apn_row = aps + h * 256;
  const float* vrow = qkv + 1024 + t;
  float a_acc = 0.f, z0 = 0.f, z1 = 0.f, z2 = 0.f;
#pragma unroll 4
  for (int m = 0; m < 256; ++m) {
    float p = apn_row[m];
    float vl = vrow[(size_t)m * 1536];
    float pv = p * vl;
    a_acc += pv;
    z0 += vecs[m] * pv;
    z1 += vecs[256 + m] * pv;
    z2 += vecs[512 + m] * pv;
  }
  attn_out[n * 512 + t] = a_acc;
  Z16[(n * 3 + 0) * 512 + t] = f2b(z0);
  Z16[(n * 3 + 1) * 512 + t] = f2b(z1);
  Z16[(n * 3 + 2) * 512 + t] = f2b(z2);
  if (t < 3) {
    float s = 0.f;
    for (int m = 0; m < 256; ++m) s += vecs[t * 256 + m];
    vsum[n * 3 + t] = s;
  }
}

// ---------------- vec layer norm max-min: du fp32 (N,3,E) -> du16 bf16
__global__ __launch_bounds__(512) void vecnorm(const float* __restrict__ du,
                                               unsigned short* __restrict__ du16)
{
  __shared__ float smx[8], smn[8];
  int n = blockIdx.x, t = threadIdx.x;
  float d0 = du[(n * 3 + 0) * 512 + t];
  float d1 = du[(n * 3 + 1) * 512 + t];
  float d2 = du[(n * 3 + 2) * 512 + t];
  float norm = sqrtf(d0 * d0 + d1 * d1 + d2 * d2);
  norm = fmaxf(norm, 1e-12f);
  float mx = norm, mn = norm;
#pragma unroll
  for (int o = 1; o < 64; o <<= 1) {
    mx = fmaxf(mx, __shfl_xor(mx, o));
    mn = fminf(mn, __shfl_xor(mn, o));
  }
  if ((t & 63) == 0) { smx[t >> 6] = mx; smn[t >> 6] = mn; }
  __syncthreads();
  float gmx = smx[0], gmn = smn[0];
#pragma unroll
  for (int i = 1; i < 8; ++i) { gmx = fmaxf(gmx, smx[i]); gmn = fminf(gmn, smn[i]); }
  float delta = gmx - gmn;
  if (delta == 0.0f) delta = 1.0f;
  float dn = fmaxf((norm - gmn) / delta, 0.0f);
  float sc = dn / norm;
  du16[(n * 3 + 0) * 512 + t] = f2b(d0 * sc);
  du16[(n * 3 + 1) * 512 + t] = f2b(d1 * sc);
  du16[(n * 3 + 2) * 512 + t] = f2b(d2 * sc);
}

extern "C" void kernel_launch(void* const* d_in, const int* in_sizes, int n_in,
                              void* d_out, int out_size, void* d_ws, size_t ws_size,
                              hipStream_t stream)
{
  const float* x    = (const float*)d_in[0];
  const float* vec  = (const float*)d_in[1];
  const float* dist = (const float*)d_in[2];
  const float* ea   = (const float*)d_in[3];
  const float* Wq   = (const float*)d_in[4];
  const float* bq   = (const float*)d_in[5];
  const float* Wk   = (const float*)d_in[6];
  const float* bk   = (const float*)d_in[7];
  const float* Wv   = (const float*)d_in[8];
  const float* bv   = (const float*)d_in[9];
  const float* Wdk  = (const float*)d_in[10];
  const float* bdk  = (const float*)d_in[11];
  const float* Wdu  = (const float*)d_in[12];
  const float* bdu  = (const float*)d_in[13];
  const float* Wdih = (const float*)d_in[14];
  const float* Wea  = (const float*)d_in[15];
  const float* bea  = (const float*)d_in[16];
  float* out_attn = (float*)d_out;
  float* out_ipe  = out_attn + 256 * 512;

  unsigned short* eab    = (unsigned short*)d_ws;       // 33554432
  unsigned short* xb     = eab + 33554432;              // 131072
  unsigned short* Wqkv_t = xb + 131072;                 // 786432 (q|k|v blocks of 512*512)
  unsigned short* Wdk_t  = Wqkv_t + 786432;             // 262144
  unsigned short* Wdu_t  = Wdk_t + 262144;              // 262144
  unsigned short* Wea_t  = Wdu_t + 262144;              // 262144
  unsigned short* Wdih_t = Wea_t + 262144;              // 524288
  unsigned short* Z16    = Wdih_t + 524288;             // 393216
  unsigned short* du16   = Z16 + 393216;                // 393216
  float* fbase = (float*)(du16 + 393216);
  float* qkvb  = fbase;            // 256*1536
  float* ksumb = qkvb + 393216;    // 2048
  float* apb   = ksumb + 2048;     // 524288
  float* vsumb = apb + 524288;     // 768
  float* dub   = vsumb + 768;      // 393216
  float* wswtb = dub + 393216;     // 786432  (~81.5 MB total)

  dim3 b256(256), b512(512);

  cvt_bf16<<<16448, b256, 0, stream>>>(ea, eab, x, xb);

  TJobs jobs;
  jobs.src[0] = Wq;   jobs.dst[0] = Wqkv_t;           jobs.E[0] = 512;
  jobs.src[1] = Wk;   jobs.dst[1] = Wqkv_t + 262144;  jobs.E[1] = 512;
  jobs.src[2] = Wv;   jobs.dst[2] = Wqkv_t + 524288;  jobs.E[2] = 512;
  jobs.src[3] = Wdk;  jobs.dst[3] = Wdk_t;            jobs.E[3] = 512;
  jobs.src[4] = Wdu;  jobs.dst[4] = Wdu_t;            jobs.E[4] = 512;
  jobs.src[5] = Wea;  jobs.dst[5] = Wea_t;            jobs.E[5] = 512;
  jobs.src[6] = Wdih; jobs.dst[6] = Wdih_t;           jobs.E[6] = 1024;
  transp_all<<<dim3(16, 32, 7), b256, 0, stream>>>(jobs);

  gemm_qkv<<<24, b256, 0, stream>>>(xb, Wqkv_t, bq, bk, bv, qkvb, ksumb);
  gemm_attn<<<2048, b256, 0, stream>>>(eab, Wdk_t, bdk, qkvb, ksumb, dist, apb);
  stage_c<<<256, b512, 0, stream>>>(apb, qkvb, vec, out_attn, Z16, vsumb);
  gemm_lin<<<24, b256, 0, stream>>>(Z16, Wdu_t, bdu, vsumb, dub, 512, 4);
  vecnorm<<<256, b512, 0, stream>>>(dub, du16);
  gemm_lin<<<48, b256, 0, stream>>>(du16, Wdih_t, nullptr, nullptr, wswtb, 1024, 8);
  gemm_ipe<<<2048, b256, 0, stream>>>(eab, Wea_t, bea, wswtb, out_ipe);
}